// Round 5
// baseline (538.648 us; speedup 1.0000x reference)
//
#include <hip/hip_runtime.h>
#include <hip/hip_bf16.h>

#define B_    32
#define LD_   512
#define LQ_   32
#define E_    300
#define NF_   4
#define D_    304
#define M_    16
#define ALPHA_ 0.9f
#define CIN_  1212          // 3*D + E
#define KP1_  1280          // CIN padded to multiple of 128 (groups of 4: 320)
#define NCOL_ 1056          // 33 columns * 32 batches
#define NPAD_ 1088          // 17 * 64
#define PPL_  9
#define NEG_N_ 128
#define NB_   272           // grid blocks (16x17 tiles)

typedef short short8 __attribute__((ext_vector_type(8)));
typedef float f32x4 __attribute__((ext_vector_type(4)));

__device__ __forceinline__ unsigned short f2bf(float f) {
    unsigned int x = __float_as_uint(f);
    unsigned int r = (x + 0x7FFFu + ((x >> 16) & 1u)) >> 16;
    return (unsigned short)r;
}

struct GemmS { unsigned short A[2][64][72]; unsigned short B[2][64][72]; };
union Shm {
    GemmS g;                                              // 36864 B
    struct { int t[3][16]; float w[3][16]; int row[3][16]; } f;
    struct { int cnt[32]; float red[256]; } l;
};

// Device-scope grid barrier (generation p = 1..5). All NB_ blocks co-resident
// (LDS 36.8KB -> >=4 blocks/CU capacity = 1088 >> 272).
__device__ __forceinline__ void grid_barrier(unsigned* cnt, unsigned* gen, unsigned p) {
    __syncthreads();
    if (threadIdx.x == 0) {
        __threadfence();   // agent release: drain + L2 writeback
        unsigned old = __hip_atomic_fetch_add(cnt, 1u, __ATOMIC_ACQ_REL,
                                              __HIP_MEMORY_SCOPE_AGENT);
        if (old == NB_ - 1) {
            __hip_atomic_store(cnt, 0u, __ATOMIC_RELAXED, __HIP_MEMORY_SCOPE_AGENT);
            __hip_atomic_fetch_add(gen, 1u, __ATOMIC_RELEASE, __HIP_MEMORY_SCOPE_AGENT);
        } else {
            long spins = 0;
            while (__hip_atomic_load(gen, __ATOMIC_ACQUIRE,
                                     __HIP_MEMORY_SCOPE_AGENT) < p) {
                __builtin_amdgcn_s_sleep(2);
                if (++spins > (1L << 24)) break;   // bailout: fail visibly, never hang
            }
        }
    }
    __syncthreads();
}

// Round-2 verified GEMM core: 64x64 tile, BK=64, double-buffered LDS,
// 4 waves as 2x2 quadrants of 32x32, each 2x2 of 16x16x32 MFMA.
__device__ __forceinline__ void gemm_core(
    const unsigned short* __restrict__ A,
    const unsigned short* __restrict__ Bm,
    int K, int m0, int n0, Shm& sh, f32x4 acc[4])
{
    int tid = threadIdx.x;
    int w = tid >> 6, lane = tid & 63;
    int wm = (w >> 1) * 32, wn = (w & 1) * 32;
    int lr = tid >> 2;
    int ls = (tid & 3) * 16;
    int fr = lane & 15, fk = (lane >> 4) * 8;

    const unsigned short* Arow = A + (size_t)(m0 + lr) * K + ls;
    const unsigned short* Brow = Bm + (size_t)(n0 + lr) * K + ls;

    #pragma unroll
    for (int t = 0; t < 4; ++t) { acc[t][0]=0.f; acc[t][1]=0.f; acc[t][2]=0.f; acc[t][3]=0.f; }

    int nk = K >> 6;
    *(uint4*)&sh.g.A[0][lr][ls]     = *(const uint4*)(Arow);
    *(uint4*)&sh.g.A[0][lr][ls + 8] = *(const uint4*)(Arow + 8);
    *(uint4*)&sh.g.B[0][lr][ls]     = *(const uint4*)(Brow);
    *(uint4*)&sh.g.B[0][lr][ls + 8] = *(const uint4*)(Brow + 8);
    __syncthreads();
    int cur = 0;
    for (int i = 0; i < nk; ++i) {
        uint4 na0, na1, nb0, nb1;
        bool more = (i + 1 < nk);
        if (more) {
            const unsigned short* An = Arow + (size_t)(i + 1) * 64;
            const unsigned short* Bn = Brow + (size_t)(i + 1) * 64;
            na0 = *(const uint4*)(An);
            na1 = *(const uint4*)(An + 8);
            nb0 = *(const uint4*)(Bn);
            nb1 = *(const uint4*)(Bn + 8);
        }
        #pragma unroll
        for (int s = 0; s < 2; ++s) {
            short8 fa0 = *(const short8*)&sh.g.A[cur][wm + fr][s * 32 + fk];
            short8 fa1 = *(const short8*)&sh.g.A[cur][wm + 16 + fr][s * 32 + fk];
            short8 fb0 = *(const short8*)&sh.g.B[cur][wn + fr][s * 32 + fk];
            short8 fb1 = *(const short8*)&sh.g.B[cur][wn + 16 + fr][s * 32 + fk];
            acc[0] = __builtin_amdgcn_mfma_f32_16x16x32_bf16(fa0, fb0, acc[0], 0, 0, 0);
            acc[1] = __builtin_amdgcn_mfma_f32_16x16x32_bf16(fa0, fb1, acc[1], 0, 0, 0);
            acc[2] = __builtin_amdgcn_mfma_f32_16x16x32_bf16(fa1, fb0, acc[2], 0, 0, 0);
            acc[3] = __builtin_amdgcn_mfma_f32_16x16x32_bf16(fa1, fb1, acc[3], 0, 0, 0);
        }
        if (more) {
            int nb = cur ^ 1;
            *(uint4*)&sh.g.A[nb][lr][ls]     = na0;
            *(uint4*)&sh.g.A[nb][lr][ls + 8] = na1;
            *(uint4*)&sh.g.B[nb][lr][ls]     = nb0;
            *(uint4*)&sh.g.B[nb][lr][ls + 8] = nb1;
        }
        __syncthreads();
        cur ^= 1;
    }
}

__device__ __forceinline__ void store_relu(
    const f32x4 acc[4], unsigned short* __restrict__ C, int M, int m0, int n0)
{
    int tid = threadIdx.x;
    int w = tid >> 6, lane = tid & 63;
    int wm = (w >> 1) * 32, wn = (w & 1) * 32;
    int rbase = (lane >> 4) * 4;
    int cb = lane & 15;
    #pragma unroll
    for (int t = 0; t < 4; ++t) {
        int MT = t >> 1, NT = t & 1;
        int m = m0 + wm + MT * 16 + rbase;
        int n = n0 + wn + NT * 16 + cb;
        ushort4 o;
        o.x = f2bf(fmaxf(acc[t][0], 0.f));
        o.y = f2bf(fmaxf(acc[t][1], 0.f));
        o.z = f2bf(fmaxf(acc[t][2], 0.f));
        o.w = f2bf(fmaxf(acc[t][3], 0.f));
        *(ushort4*)(C + (size_t)n * M + m) = o;
    }
}

__global__ __launch_bounds__(256, 2) void fofe_fused(
    const int* __restrict__ doc, const float* __restrict__ doc_f,
    const int* __restrict__ query,
    const int* __restrict__ target_s, const int* __restrict__ target_e,
    const float* __restrict__ emb,
    const int* __restrict__ rand_length, const int* __restrict__ rand_position,
    const int* __restrict__ rand_idx,
    const float* __restrict__ W1, const float* __restrict__ W2,
    const float* __restrict__ W3, const float* __restrict__ W4,
    const float* __restrict__ W5,
    unsigned short* __restrict__ W1b, unsigned short* __restrict__ W2b,
    unsigned short* __restrict__ W3b, unsigned short* __restrict__ W4b,
    unsigned short* __restrict__ Ft,
    unsigned short* __restrict__ hA, unsigned short* __restrict__ hB,
    unsigned short* __restrict__ hC,
    float* __restrict__ zbuf, unsigned* __restrict__ bar,
    float* __restrict__ out)
{
    __shared__ Shm sh;
    int bid = blockIdx.x, tid = threadIdx.x;
    unsigned* cnt = bar;
    unsigned* gen = bar + 1;

    // ============ phase 0: features + weight conversion + zbuf ============
    for (int j = 0; j < 4; ++j) {
        int col = bid * 4 + j;                 // 0..1087, exactly covers NPAD_
        bool real = (col < NCOL_);
        int b = col / 33, c33 = col % 33;
        if (real && tid < 48) {
            int part = tid >> 4, k = tid & 15;
            int t; float valid;
            if (c33 == 0) {
                int ts = target_s[b], te = target_e[b];
                int span = te - ts;
                if (part == 0)      { t = ts - 1 - k;  valid = (t >= 0) ? 1.f : 0.f; }
                else if (part == 1) { t = te - k;      valid = (k <= span && t >= 0) ? 1.f : 0.f; }
                else                { t = te + 1 + k;  valid = (t < LD_) ? 1.f : 0.f; }
            } else {
                int jj = c33 - 1;
                int r = jj / PPL_, p = jj - r * PPL_;
                int rl = rand_length[r];
                int rp = rand_position[r * PPL_ + p];
                if (part == 0)      { t = rp - 1 - k;      valid = (t >= 0) ? 1.f : 0.f; }
                else if (part == 1) { t = rp - k;          valid = (k <= rl && t >= 0) ? 1.f : 0.f; }
                else                { t = rp + rl + 1 + k; valid = (t < LD_) ? 1.f : 0.f; }
            }
            float wv = (valid != 0.f) ? powf(ALPHA_, (float)k) : 0.f;
            t = min(max(t, 0), LD_ - 1);
            sh.f.t[part][k] = t;
            sh.f.w[part][k] = wv;
            sh.f.row[part][k] = doc[b * LD_ + t];
        }
        __syncthreads();
        unsigned short* o4 = Ft + (size_t)col * KP1_;
        for (int g = tid; g < 320; g += 256) {
            ushort4 o; o.x = 0; o.y = 0; o.z = 0; o.w = 0;
            if (real && g < 228) {             // doc parts: 3 * 76 groups
                int part = g / 76;
                int g2 = g - part * 76;
                int cc = g2 * 4;
                float ax = 0.f, ay = 0.f, az = 0.f, aw = 0.f;
                if (cc < 300) {
                    for (int i = 0; i < 16; ++i) {
                        float4 v = *(const float4*)(emb + (size_t)sh.f.row[part][i] * E_ + cc);
                        float wv = sh.f.w[part][i];
                        ax += wv * v.x; ay += wv * v.y; az += wv * v.z; aw += wv * v.w;
                    }
                } else {
                    for (int i = 0; i < 16; ++i) {
                        float4 v = *(const float4*)(doc_f + ((size_t)b * LD_ + sh.f.t[part][i]) * NF_);
                        float wv = sh.f.w[part][i];
                        ax += wv * v.x; ay += wv * v.y; az += wv * v.z; aw += wv * v.w;
                    }
                }
                o.x = f2bf(ax); o.y = f2bf(ay); o.z = f2bf(az); o.w = f2bf(aw);
            } else if (real && g < 303) {      // query FOFE: ce = (g-228)*4
                int ce = (g - 228) * 4;
                float ax = 0.f, ay = 0.f, az = 0.f, aw = 0.f;
                float wv = powf(ALPHA_, (float)(LQ_ - 1));
                for (int i = 0; i < 32; ++i) {
                    int row = query[b * LQ_ + i];
                    float4 v = *(const float4*)(emb + (size_t)row * E_ + ce);
                    ax += wv * v.x; ay += wv * v.y; az += wv * v.z; aw += wv * v.w;
                    wv *= (1.0f / ALPHA_);
                }
                o.x = f2bf(ax); o.y = f2bf(ay); o.z = f2bf(az); o.w = f2bf(aw);
            }
            *(ushort4*)(o4 + 4 * g) = o;
        }
        __syncthreads();
    }
    if (tid < 4) zbuf[bid * 4 + tid] = 0.f;

    {   // weight conversion, grid-stride over ushort4 groups
        const long n1 = 1024L * 320;               // W1 K-padded to 1280
        const long n2 = 1024L * 1024L / 4;
        const long n4 = 512L * 1024L / 4;
        const long total = n1 + 2 * n2 + n4;
        const long stride = (long)NB_ * 256;
        for (long i = (long)bid * 256 + tid; i < total; i += stride) {
            ushort4 o;
            if (i < n1) {
                long m = i / 320; int k4 = (int)(i - m * 320);
                if (k4 < 303) {
                    float4 v = *(const float4*)(W1 + m * CIN_ + k4 * 4);
                    o.x = f2bf(v.x); o.y = f2bf(v.y); o.z = f2bf(v.z); o.w = f2bf(v.w);
                } else { o.x = 0; o.y = 0; o.z = 0; o.w = 0; }
                *(ushort4*)(W1b + i * 4) = o;
            } else if (i < n1 + n2) {
                long jj = i - n1;
                float4 v = *(const float4*)(W2 + jj * 4);
                o.x = f2bf(v.x); o.y = f2bf(v.y); o.z = f2bf(v.z); o.w = f2bf(v.w);
                *(ushort4*)(W2b + jj * 4) = o;
            } else if (i < n1 + 2 * n2) {
                long jj = i - n1 - n2;
                float4 v = *(const float4*)(W3 + jj * 4);
                o.x = f2bf(v.x); o.y = f2bf(v.y); o.z = f2bf(v.z); o.w = f2bf(v.w);
                *(ushort4*)(W3b + jj * 4) = o;
            } else {
                long jj = i - n1 - 2 * n2;
                float4 v = *(const float4*)(W4 + jj * 4);
                o.x = f2bf(v.x); o.y = f2bf(v.y); o.z = f2bf(v.z); o.w = f2bf(v.w);
                *(ushort4*)(W4b + jj * 4) = o;
            }
        }
    }
    grid_barrier(cnt, gen, 1);

    // ============ L1: hA = relu(W1b . Ft^T) ============
    {
        int m0 = (bid & 15) << 6, n0 = (bid >> 4) << 6;
        f32x4 acc[4];
        gemm_core(W1b, Ft, KP1_, m0, n0, sh, acc);
        store_relu(acc, hA, 1024, m0, n0);
    }
    grid_barrier(cnt, gen, 2);

    // ============ L2 ============
    {
        int m0 = (bid & 15) << 6, n0 = (bid >> 4) << 6;
        f32x4 acc[4];
        gemm_core(W2b, hA, 1024, m0, n0, sh, acc);
        store_relu(acc, hB, 1024, m0, n0);
    }
    grid_barrier(cnt, gen, 3);

    // ============ L3 ============
    {
        int m0 = (bid & 15) << 6, n0 = (bid >> 4) << 6;
        f32x4 acc[4];
        gemm_core(W3b, hB, 1024, m0, n0, sh, acc);
        store_relu(acc, hC, 1024, m0, n0);
    }
    grid_barrier(cnt, gen, 4);

    // ============ L4 + score partials: zbuf[n] += relu(h4).W5 ============
    if (bid < 136) {
        int m0 = (bid & 7) << 6, n0 = (bid >> 3) << 6;
        f32x4 acc[4];
        gemm_core(W4b, hC, 1024, m0, n0, sh, acc);
        int w = tid >> 6, lane = tid & 63;
        int wm = (w >> 1) * 32, wn = (w & 1) * 32;
        int fr = lane & 15, fq = lane >> 4;
        #pragma unroll
        for (int NT = 0; NT < 2; ++NT) {
            float p = 0.f;
            #pragma unroll
            for (int MT = 0; MT < 2; ++MT) {
                const f32x4 a = acc[MT * 2 + NT];
                int mb = m0 + wm + MT * 16 + fq * 4;
                p += fmaxf(a[0], 0.f) * W5[mb]
                   + fmaxf(a[1], 0.f) * W5[mb + 1]
                   + fmaxf(a[2], 0.f) * W5[mb + 2]
                   + fmaxf(a[3], 0.f) * W5[mb + 3];
            }
            p += __shfl_down(p, 32);
            p += __shfl_down(p, 16);
            if (fq == 0) {
                int n = n0 + wn + NT * 16 + fr;
                atomicAdd(&zbuf[n], p);
            }
        }
    }
    grid_barrier(cnt, gen, 5);

    // ============ loss (block 0 only) ============
    if (bid == 0) {
        if (tid < 32) sh.l.cnt[tid] = 0;
        __syncthreads();
        if (tid < NEG_N_) atomicAdd(&sh.l.cnt[rand_idx[tid]], 1);
        __syncthreads();
        float acc = 0.f;
        for (int c = tid; c < NCOL_; c += 256) {
            float z = __hip_atomic_load(&zbuf[c], __ATOMIC_ACQUIRE,
                                        __HIP_MEMORY_SCOPE_AGENT);
            float s = 1.f / (1.f + expf(-z));
            int c33 = c % 33;
            if (c33 == 0) { float d = s - 1.f; acc += 128.f * d * d; }
            else          { acc += (float)sh.l.cnt[c33 - 1] * s * s; }
        }
        sh.l.red[tid] = acc;
        __syncthreads();
        for (int o = 128; o > 0; o >>= 1) {
            if (tid < o) sh.l.red[tid] += sh.l.red[tid + o];
            __syncthreads();
        }
        if (tid == 0) out[0] = sh.l.red[0];
    }
}

extern "C" void kernel_launch(void* const* d_in, const int* in_sizes, int n_in,
                              void* d_out, int out_size, void* d_ws, size_t ws_size,
                              hipStream_t stream)
{
    const int*   doc        = (const int*)d_in[0];
    const float* doc_f      = (const float*)d_in[1];
    const int*   query      = (const int*)d_in[2];
    const int*   target_s   = (const int*)d_in[3];
    const int*   target_e   = (const int*)d_in[4];
    const float* emb        = (const float*)d_in[7];
    const float* W1         = (const float*)d_in[8];
    const float* W2         = (const float*)d_in[9];
    const float* W3         = (const float*)d_in[10];
    const float* W4         = (const float*)d_in[11];
    const float* W5         = (const float*)d_in[12];
    const int*   rand_length   = (const int*)d_in[13];
    const int*   rand_position = (const int*)d_in[14];
    const int*   rand_idx      = (const int*)d_in[15];

    char* ws = (char*)d_ws;
    size_t off = 0;
    auto alloc = [&](size_t bytes) {
        void* p = ws + off;
        off = (off + bytes + 255) & ~(size_t)255;
        return p;
    };
    unsigned short* W1b = (unsigned short*)alloc((size_t)1024 * KP1_ * 2);
    unsigned short* W2b = (unsigned short*)alloc((size_t)1024 * 1024 * 2);
    unsigned short* W3b = (unsigned short*)alloc((size_t)1024 * 1024 * 2);
    unsigned short* W4b = (unsigned short*)alloc((size_t)512 * 1024 * 2);
    unsigned short* Ft  = (unsigned short*)alloc((size_t)NPAD_ * KP1_ * 2);
    unsigned short* hA  = (unsigned short*)alloc((size_t)NPAD_ * 1024 * 2);
    unsigned short* hB  = (unsigned short*)alloc((size_t)NPAD_ * 1024 * 2);
    unsigned short* hC  = (unsigned short*)alloc((size_t)NPAD_ * 1024 * 2);
    float*    zbuf      = (float*)alloc((size_t)NPAD_ * sizeof(float));
    unsigned* bar       = (unsigned*)alloc(256);
    (void)ws_size; (void)in_sizes; (void)n_in; (void)out_size;

    hipMemsetAsync(bar, 0, 2 * sizeof(unsigned), stream);

    fofe_fused<<<dim3(NB_), dim3(256), 0, stream>>>(
        doc, doc_f, query, target_s, target_e, emb,
        rand_length, rand_position, rand_idx,
        W1, W2, W3, W4, W5,
        W1b, W2b, W3b, W4b, Ft, hA, hB, hC,
        zbuf, bar, (float*)d_out);
}

// Round 6
// 189.147 us; speedup vs baseline: 2.8478x; 2.8478x over previous
//
#include <hip/hip_runtime.h>
#include <hip/hip_bf16.h>

#define B_    32
#define LD_   512
#define LQ_   32
#define E_    300
#define NF_   4
#define D_    304
#define M_    16
#define ALPHA_ 0.9f
#define CIN_  1212          // 3*D + E
#define KP1_  1280          // CIN padded to multiple of 64
#define NCOL_ 1056          // 33 columns * 32 batches
#define NPAD_ 1088          // 17 * 64
#define PPL_  9
#define NEG_N_ 128

typedef short short8 __attribute__((ext_vector_type(8)));
typedef float f32x4 __attribute__((ext_vector_type(4)));

__device__ __forceinline__ unsigned short f2bf(float f) {
    unsigned int x = __float_as_uint(f);
    unsigned int r = (x + 0x7FFFu + ((x >> 16) & 1u)) >> 16;
    return (unsigned short)r;
}

// ---------------------------------------------------------------------------
// prep: blockIdx branches
//   [0,1056)    feature columns (query FOFE inlined)
//   [1056,2000) weight fp32->bf16 (grid-stride)
//   [2000,2032) zero Ft pad rows
//   2032        zero zbuf + done counter
// ---------------------------------------------------------------------------
__global__ __launch_bounds__(320) void prep(
    const int* __restrict__ doc, const float* __restrict__ doc_f,
    const int* __restrict__ query,
    const int* __restrict__ target_s, const int* __restrict__ target_e,
    const float* __restrict__ emb,
    const int* __restrict__ rand_length, const int* __restrict__ rand_position,
    const float* __restrict__ W1, const float* __restrict__ W2,
    const float* __restrict__ W3, const float* __restrict__ W4,
    unsigned short* __restrict__ W1b, unsigned short* __restrict__ W2b,
    unsigned short* __restrict__ W3b, unsigned short* __restrict__ W4b,
    unsigned short* __restrict__ Ft, float* __restrict__ zbuf,
    unsigned* __restrict__ done)
{
    int bid = blockIdx.x;
    int tid = threadIdx.x;

    if (bid < NCOL_) {
        int b = bid / 33;
        int col = bid % 33;
        __shared__ int   s_t[3][16];
        __shared__ float s_w[3][16];
        __shared__ int   s_row[3][16];
        if (tid < 48) {
            int part = tid >> 4, k = tid & 15;
            int t; float valid;
            if (col == 0) {
                int ts = target_s[b], te = target_e[b];
                int span = te - ts;
                if (part == 0)      { t = ts - 1 - k;  valid = (t >= 0) ? 1.f : 0.f; }
                else if (part == 1) { t = te - k;      valid = (k <= span && t >= 0) ? 1.f : 0.f; }
                else                { t = te + 1 + k;  valid = (t < LD_) ? 1.f : 0.f; }
            } else {
                int j = col - 1;
                int r = j / PPL_, p = j - r * PPL_;
                int rl = rand_length[r];
                int rp = rand_position[r * PPL_ + p];
                if (part == 0)      { t = rp - 1 - k;      valid = (t >= 0) ? 1.f : 0.f; }
                else if (part == 1) { t = rp - k;          valid = (k <= rl && t >= 0) ? 1.f : 0.f; }
                else                { t = rp + rl + 1 + k; valid = (t < LD_) ? 1.f : 0.f; }
            }
            float w = (valid != 0.f) ? powf(ALPHA_, (float)k) : 0.f;
            t = min(max(t, 0), LD_ - 1);
            s_t[part][k] = t;
            s_w[part][k] = w;
            s_row[part][k] = doc[b * LD_ + t];
        }
        __syncthreads();

        unsigned short* out = Ft + (size_t)bid * KP1_;
        int g = tid;                       // 320 groups of 4 elements (K=1280)
        if (g < 228) {                     // doc parts: 3 * 76 groups
            int part = g / 76;
            int g2 = g - part * 76;
            int cc = g2 * 4;
            float ax = 0.f, ay = 0.f, az = 0.f, aw = 0.f;
            if (cc < 300) {
                for (int i = 0; i < 16; ++i) {
                    float4 v = *(const float4*)(emb + (size_t)s_row[part][i] * E_ + cc);
                    float wv = s_w[part][i];
                    ax += wv * v.x; ay += wv * v.y; az += wv * v.z; aw += wv * v.w;
                }
            } else {
                for (int i = 0; i < 16; ++i) {
                    float4 v = *(const float4*)(doc_f + ((size_t)b * LD_ + s_t[part][i]) * NF_);
                    float wv = s_w[part][i];
                    ax += wv * v.x; ay += wv * v.y; az += wv * v.z; aw += wv * v.w;
                }
            }
            ushort4 o; o.x = f2bf(ax); o.y = f2bf(ay); o.z = f2bf(az); o.w = f2bf(aw);
            *(ushort4*)(out + 4 * g) = o;
        } else if (g < 303) {              // query FOFE, ce = (g-228)*4
            int ce = (g - 228) * 4;
            float ax = 0.f, ay = 0.f, az = 0.f, aw = 0.f;
            float wv = powf(ALPHA_, (float)(LQ_ - 1));
            for (int i = 0; i < 32; ++i) {
                int row = query[b * LQ_ + i];
                float4 v = *(const float4*)(emb + (size_t)row * E_ + ce);
                ax += wv * v.x; ay += wv * v.y; az += wv * v.z; aw += wv * v.w;
                wv *= (1.0f / ALPHA_);
            }
            ushort4 o; o.x = f2bf(ax); o.y = f2bf(ay); o.z = f2bf(az); o.w = f2bf(aw);
            *(ushort4*)(out + 4 * g) = o;
        } else {                           // K padding 1212..1279
            ushort4 z; z.x = 0; z.y = 0; z.z = 0; z.w = 0;
            *(ushort4*)(out + 4 * g) = z;
        }
    } else if (bid < 2000) {
        const long n1 = 1024L * 320;                 // W1 groups (K-padded)
        const long n2 = 1024L * 1024L / 4;
        const long n4 = 512L * 1024L / 4;
        const long total = n1 + 2 * n2 + n4;
        long stride = 944L * 320L;
        for (long i = (long)(bid - NCOL_) * 320L + tid; i < total; i += stride) {
            ushort4 o;
            if (i < n1) {
                long m = i / 320; int k4 = (int)(i - m * 320);
                if (k4 < 303) {
                    float4 v = *(const float4*)(W1 + m * CIN_ + k4 * 4);
                    o.x = f2bf(v.x); o.y = f2bf(v.y); o.z = f2bf(v.z); o.w = f2bf(v.w);
                } else { o.x = 0; o.y = 0; o.z = 0; o.w = 0; }
                *(ushort4*)(W1b + i * 4) = o;
            } else if (i < n1 + n2) {
                long j = i - n1;
                float4 v = *(const float4*)(W2 + j * 4);
                o.x = f2bf(v.x); o.y = f2bf(v.y); o.z = f2bf(v.z); o.w = f2bf(v.w);
                *(ushort4*)(W2b + j * 4) = o;
            } else if (i < n1 + 2 * n2) {
                long j = i - n1 - n2;
                float4 v = *(const float4*)(W3 + j * 4);
                o.x = f2bf(v.x); o.y = f2bf(v.y); o.z = f2bf(v.z); o.w = f2bf(v.w);
                *(ushort4*)(W3b + j * 4) = o;
            } else {
                long j = i - n1 - 2 * n2;
                float4 v = *(const float4*)(W4 + j * 4);
                o.x = f2bf(v.x); o.y = f2bf(v.y); o.z = f2bf(v.z); o.w = f2bf(v.w);
                *(ushort4*)(W4b + j * 4) = o;
            }
        }
    } else if (bid < 2032) {
        int row = NCOL_ + (bid - 2000);
        ushort4 z; z.x = 0; z.y = 0; z.z = 0; z.w = 0;
        *(ushort4*)(Ft + (size_t)row * KP1_ + tid * 4) = z;
    } else {
        for (int i = tid; i < NPAD_; i += 320) zbuf[i] = 0.f;
        if (tid == 0) *done = 0u;
    }
}

// ---------------------------------------------------------------------------
// Round-2 proven GEMM core: 64x64 tile, BK=64, double-buffered LDS,
// 4 waves = 2x2 quadrants of 32x32, each 2x2 of 16x16x32 MFMA.
// ---------------------------------------------------------------------------
struct GemmS { unsigned short A[2][64][72]; unsigned short B[2][64][72]; };

__device__ __forceinline__ void gemm_core(
    const unsigned short* __restrict__ A,
    const unsigned short* __restrict__ Bm,
    int K, int m0, int n0, GemmS& sh, f32x4 acc[4])
{
    int tid = threadIdx.x;
    int w = tid >> 6, lane = tid & 63;
    int wm = (w >> 1) * 32, wn = (w & 1) * 32;
    int lr = tid >> 2;
    int ls = (tid & 3) * 16;
    int fr = lane & 15, fk = (lane >> 4) * 8;

    const unsigned short* Arow = A + (size_t)(m0 + lr) * K + ls;
    const unsigned short* Brow = Bm + (size_t)(n0 + lr) * K + ls;

    #pragma unroll
    for (int t = 0; t < 4; ++t) { acc[t][0]=0.f; acc[t][1]=0.f; acc[t][2]=0.f; acc[t][3]=0.f; }

    int nk = K >> 6;
    *(uint4*)&sh.A[0][lr][ls]     = *(const uint4*)(Arow);
    *(uint4*)&sh.A[0][lr][ls + 8] = *(const uint4*)(Arow + 8);
    *(uint4*)&sh.B[0][lr][ls]     = *(const uint4*)(Brow);
    *(uint4*)&sh.B[0][lr][ls + 8] = *(const uint4*)(Brow + 8);
    __syncthreads();
    int cur = 0;
    for (int i = 0; i < nk; ++i) {
        uint4 na0, na1, nb0, nb1;
        bool more = (i + 1 < nk);
        if (more) {
            const unsigned short* An = Arow + (size_t)(i + 1) * 64;
            const unsigned short* Bn = Brow + (size_t)(i + 1) * 64;
            na0 = *(const uint4*)(An);
            na1 = *(const uint4*)(An + 8);
            nb0 = *(const uint4*)(Bn);
            nb1 = *(const uint4*)(Bn + 8);
        }
        #pragma unroll
        for (int s = 0; s < 2; ++s) {
            short8 fa0 = *(const short8*)&sh.A[cur][wm + fr][s * 32 + fk];
            short8 fa1 = *(const short8*)&sh.A[cur][wm + 16 + fr][s * 32 + fk];
            short8 fb0 = *(const short8*)&sh.B[cur][wn + fr][s * 32 + fk];
            short8 fb1 = *(const short8*)&sh.B[cur][wn + 16 + fr][s * 32 + fk];
            acc[0] = __builtin_amdgcn_mfma_f32_16x16x32_bf16(fa0, fb0, acc[0], 0, 0, 0);
            acc[1] = __builtin_amdgcn_mfma_f32_16x16x32_bf16(fa0, fb1, acc[1], 0, 0, 0);
            acc[2] = __builtin_amdgcn_mfma_f32_16x16x32_bf16(fa1, fb0, acc[2], 0, 0, 0);
            acc[3] = __builtin_amdgcn_mfma_f32_16x16x32_bf16(fa1, fb1, acc[3], 0, 0, 0);
        }
        if (more) {
            int nb = cur ^ 1;
            *(uint4*)&sh.A[nb][lr][ls]     = na0;
            *(uint4*)&sh.A[nb][lr][ls + 8] = na1;
            *(uint4*)&sh.B[nb][lr][ls]     = nb0;
            *(uint4*)&sh.B[nb][lr][ls + 8] = nb1;
        }
        __syncthreads();
        cur ^= 1;
    }
}

__global__ __launch_bounds__(256) void gemm_relu(
    const unsigned short* __restrict__ A,
    const unsigned short* __restrict__ Bm,
    unsigned short* __restrict__ C, int M, int K)
{
    __shared__ GemmS sh;
    int m0 = blockIdx.x * 64, n0 = blockIdx.y * 64;
    f32x4 acc[4];
    gemm_core(A, Bm, K, m0, n0, sh, acc);
    int tid = threadIdx.x;
    int w = tid >> 6, lane = tid & 63;
    int wm = (w >> 1) * 32, wn = (w & 1) * 32;
    int rbase = (lane >> 4) * 4;
    int cb = lane & 15;
    #pragma unroll
    for (int t = 0; t < 4; ++t) {
        int MT = t >> 1, NT = t & 1;
        int m = m0 + wm + MT * 16 + rbase;
        int n = n0 + wn + NT * 16 + cb;
        ushort4 o;
        o.x = f2bf(fmaxf(acc[t][0], 0.f));
        o.y = f2bf(fmaxf(acc[t][1], 0.f));
        o.z = f2bf(fmaxf(acc[t][2], 0.f));
        o.w = f2bf(fmaxf(acc[t][3], 0.f));
        *(ushort4*)(C + (size_t)n * M + m) = o;
    }
}

// ---------------------------------------------------------------------------
// L4 + score partials + loss-by-last-block. grid (8,17) = 136 blocks.
// z[n] += sum_m relu(h4[m][n]) * W5[m]; last block to finish computes loss.
// ---------------------------------------------------------------------------
__global__ __launch_bounds__(256) void gemm4_score_loss(
    const unsigned short* __restrict__ A,
    const unsigned short* __restrict__ Bm,
    const float* __restrict__ W5, const int* __restrict__ rand_idx,
    float* __restrict__ zbuf, unsigned* __restrict__ done,
    float* __restrict__ out, int M, int K)
{
    __shared__ GemmS sh;
    __shared__ int s_flag;
    __shared__ int s_cnt[32];
    __shared__ float s_red[256];
    int m0 = blockIdx.x * 64, n0 = blockIdx.y * 64;
    f32x4 acc[4];
    gemm_core(A, Bm, K, m0, n0, sh, acc);
    int tid = threadIdx.x;
    int w = tid >> 6, lane = tid & 63;
    int wm = (w >> 1) * 32, wn = (w & 1) * 32;
    int fr = lane & 15, fq = lane >> 4;
    #pragma unroll
    for (int NT = 0; NT < 2; ++NT) {
        float p = 0.f;
        #pragma unroll
        for (int MT = 0; MT < 2; ++MT) {
            const f32x4 a = acc[MT * 2 + NT];
            int mb = m0 + wm + MT * 16 + fq * 4;
            p += fmaxf(a[0], 0.f) * W5[mb]
               + fmaxf(a[1], 0.f) * W5[mb + 1]
               + fmaxf(a[2], 0.f) * W5[mb + 2]
               + fmaxf(a[3], 0.f) * W5[mb + 3];
        }
        p += __shfl_down(p, 32);
        p += __shfl_down(p, 16);
        if (fq == 0) {
            int n = n0 + wn + NT * 16 + fr;
            atomicAdd(&zbuf[n], p);
        }
    }
    __syncthreads();   // drains vmcnt: this block's zbuf atomics complete
    if (tid == 0) {
        unsigned old = __hip_atomic_fetch_add(done, 1u, __ATOMIC_ACQ_REL,
                                              __HIP_MEMORY_SCOPE_AGENT);
        s_flag = (old == 8 * 17 - 1) ? 1 : 0;
    }
    __syncthreads();
    if (s_flag) {      // last block: all zbuf adds visible (acquire on done)
        if (tid < 32) s_cnt[tid] = 0;
        __syncthreads();
        if (tid < NEG_N_) atomicAdd(&s_cnt[rand_idx[tid]], 1);
        __syncthreads();
        float accv = 0.f;
        for (int c = tid; c < NCOL_; c += 256) {
            float z = __hip_atomic_load(&zbuf[c], __ATOMIC_ACQUIRE,
                                        __HIP_MEMORY_SCOPE_AGENT);
            float s = 1.f / (1.f + expf(-z));
            int c33 = c % 33;
            if (c33 == 0) { float d = s - 1.f; accv += 128.f * d * d; }
            else          { accv += (float)s_cnt[c33 - 1] * s * s; }
        }
        s_red[tid] = accv;
        __syncthreads();
        for (int o = 128; o > 0; o >>= 1) {
            if (tid < o) s_red[tid] += s_red[tid + o];
            __syncthreads();
        }
        if (tid == 0) out[0] = s_red[0];
    }
}

extern "C" void kernel_launch(void* const* d_in, const int* in_sizes, int n_in,
                              void* d_out, int out_size, void* d_ws, size_t ws_size,
                              hipStream_t stream)
{
    const int*   doc        = (const int*)d_in[0];
    const float* doc_f      = (const float*)d_in[1];
    const int*   query      = (const int*)d_in[2];
    const int*   target_s   = (const int*)d_in[3];
    const int*   target_e   = (const int*)d_in[4];
    const float* emb        = (const float*)d_in[7];
    const float* W1         = (const float*)d_in[8];
    const float* W2         = (const float*)d_in[9];
    const float* W3         = (const float*)d_in[10];
    const float* W4         = (const float*)d_in[11];
    const float* W5         = (const float*)d_in[12];
    const int*   rand_length   = (const int*)d_in[13];
    const int*   rand_position = (const int*)d_in[14];
    const int*   rand_idx      = (const int*)d_in[15];

    char* ws = (char*)d_ws;
    size_t off = 0;
    auto alloc = [&](size_t bytes) {
        void* p = ws + off;
        off = (off + bytes + 255) & ~(size_t)255;
        return p;
    };
    unsigned short* W1b = (unsigned short*)alloc((size_t)1024 * KP1_ * 2);
    unsigned short* W2b = (unsigned short*)alloc((size_t)1024 * 1024 * 2);
    unsigned short* W3b = (unsigned short*)alloc((size_t)1024 * 1024 * 2);
    unsigned short* W4b = (unsigned short*)alloc((size_t)512 * 1024 * 2);
    unsigned short* Ft  = (unsigned short*)alloc((size_t)NPAD_ * KP1_ * 2);
    unsigned short* hA  = (unsigned short*)alloc((size_t)NPAD_ * 1024 * 2);
    unsigned short* hB  = (unsigned short*)alloc((size_t)NPAD_ * 1024 * 2);
    float*    zbuf      = (float*)alloc((size_t)NPAD_ * sizeof(float));
    unsigned* done      = (unsigned*)alloc(256);
    (void)ws_size; (void)in_sizes; (void)n_in; (void)out_size;

    prep<<<dim3(2033), dim3(320), 0, stream>>>(
        doc, doc_f, query, target_s, target_e, emb,
        rand_length, rand_position,
        W1, W2, W3, W4, W1b, W2b, W3b, W4b, Ft, zbuf, done);

    gemm_relu<<<dim3(16, 17), dim3(256), 0, stream>>>(W1b, Ft, hA, 1024, KP1_);
    gemm_relu<<<dim3(16, 17), dim3(256), 0, stream>>>(W2b, hA, hB, 1024, 1024);
    gemm_relu<<<dim3(16, 17), dim3(256), 0, stream>>>(W3b, hB, hA, 1024, 1024);
    gemm4_score_loss<<<dim3(8, 17), dim3(256), 0, stream>>>(
        W4b, hA, W5, rand_idx, zbuf, done, (float*)d_out, 512, 1024);
}